// Round 4
// baseline (300.136 us; speedup 1.0000x reference)
//
#include <hip/hip_runtime.h>
#include <hip/hip_bf16.h>
#include <math.h>

#define N_NODES 100000
#define N_EDGES 1600000
#define NEG_SLOPE 0.2f

// bucket = dst >> 7 : 128 nodes per bucket
#define NB_BUCKET 782
#define ST_CAP 2560

// ---- workspace layout (bytes) ----
#define OFF_H     0              // N*128 bf16 = 25,600,000 (uint4 granular)
#define OFF_ASRC  25600000       // N*4 f32
#define OFF_ADST  27200000       // N*4 f32
#define OFF_OFFS  28800000       // (N+1) int (pad)
#define OFF_BCNT  29200128       // 782 int (pad 4096)
#define OFF_BOFF  29204224       // 783 int (pad 4096)
#define OFF_BCUR  29208320       // 782 int (pad 4096)
#define OFF_TMP   29212416       // E uint
#define OFF_CSR   35612416       // E int
// total ≈ 42.0 MB

__device__ __forceinline__ float leaky(float x) {
    return fmaxf(x, NEG_SLOPE * x);
}
__device__ __forceinline__ unsigned int pack_bf2(float a, float b) {
    unsigned int ua = (unsigned int)__bfloat16_as_ushort(__float2bfloat16(a));
    unsigned int ub = (unsigned int)__bfloat16_as_ushort(__float2bfloat16(b));
    return ua | (ub << 16);
}
__device__ __forceinline__ float bf_lo(unsigned int u) {
    return __uint_as_float(u << 16);
}
__device__ __forceinline__ float bf_hi(unsigned int u) {
    return __uint_as_float(u & 0xffff0000u);
}

// ---------------------------------------------------------------------------
// K1: h = x @ W. 128x128 block tile, 8x8 micro-tile, fused attention epilogue.
// h stored as bf16 packed uint4 (8 channels / 16B): h4[row*16 + cgrp].
// ---------------------------------------------------------------------------
#define BR2 128
__global__ __launch_bounds__(256, 2) void gemm_att_kernel(
    const float* __restrict__ x, const float* __restrict__ W,
    const float* __restrict__ att_src, const float* __restrict__ att_dst,
    uint4* __restrict__ h4, float* __restrict__ a_src, float* __restrict__ a_dst)
{
    __shared__ float xs[32][BR2 + 4];   // [k][row]
    __shared__ float ws[32][132];       // [k][col]

    const int tid = threadIdx.x;
    const int cx  = tid & 15;           // cols cx*8 .. cx*8+7
    const int ry  = tid >> 4;           // rows ry*8 .. ry*8+7
    const int n0  = blockIdx.x * BR2;

    float acc[8][8];
#pragma unroll
    for (int i = 0; i < 8; ++i)
#pragma unroll
        for (int j = 0; j < 8; ++j) acc[i][j] = 0.f;

    // staging assignments
    const int xr  = tid >> 1;           // 0..127 (row)
    const int xk0 = (tid & 1) * 16;     // k base (covers 16 k via 4 float4)
    const int wk  = tid >> 3;           // 0..31 (k)
    const int wc0 = (tid & 7) * 16;     // col base (covers 16 cols)

    for (int k0 = 0; k0 < 128; k0 += 32) {
        {
            int row = n0 + xr;
            row = row < N_NODES ? row : N_NODES - 1;
            const float4* xp = (const float4*)&x[(size_t)row * 128 + k0 + xk0];
#pragma unroll
            for (int i = 0; i < 4; ++i) {
                const float4 v = xp[i];
                xs[xk0 + i * 4 + 0][xr] = v.x;
                xs[xk0 + i * 4 + 1][xr] = v.y;
                xs[xk0 + i * 4 + 2][xr] = v.z;
                xs[xk0 + i * 4 + 3][xr] = v.w;
            }
        }
        {
            const float4* wp = (const float4*)&W[(size_t)(k0 + wk) * 128 + wc0];
#pragma unroll
            for (int i = 0; i < 4; ++i)
                *(float4*)&ws[wk][wc0 + i * 4] = wp[i];
        }
        __syncthreads();

#pragma unroll 2
        for (int k = 0; k < 32; ++k) {
            const float4 xa = *(const float4*)&xs[k][ry * 8];
            const float4 xb = *(const float4*)&xs[k][ry * 8 + 4];
            const float4 wa = *(const float4*)&ws[k][cx * 8];
            const float4 wb = *(const float4*)&ws[k][cx * 8 + 4];
            const float xv[8] = {xa.x, xa.y, xa.z, xa.w, xb.x, xb.y, xb.z, xb.w};
            const float wv[8] = {wa.x, wa.y, wa.z, wa.w, wb.x, wb.y, wb.z, wb.w};
#pragma unroll
            for (int i = 0; i < 8; ++i)
#pragma unroll
                for (int j = 0; j < 8; ++j)
                    acc[i][j] = fmaf(xv[i], wv[j], acc[i][j]);
        }
        __syncthreads();
    }

    // epilogue: bf16 h + attention partials
    float as8[8], ad8[8];
    {
        const float4 a0 = ((const float4*)att_src)[cx * 2];
        const float4 a1 = ((const float4*)att_src)[cx * 2 + 1];
        const float4 b0 = ((const float4*)att_dst)[cx * 2];
        const float4 b1 = ((const float4*)att_dst)[cx * 2 + 1];
        as8[0]=a0.x; as8[1]=a0.y; as8[2]=a0.z; as8[3]=a0.w;
        as8[4]=a1.x; as8[5]=a1.y; as8[6]=a1.z; as8[7]=a1.w;
        ad8[0]=b0.x; ad8[1]=b0.y; ad8[2]=b0.z; ad8[3]=b0.w;
        ad8[4]=b1.x; ad8[5]=b1.y; ad8[6]=b1.z; ad8[7]=b1.w;
    }
    const int head = cx >> 2;

#pragma unroll
    for (int i = 0; i < 8; ++i) {
        const int row = n0 + ry * 8 + i;
        if (row >= N_NODES) break;
        uint4 pk;
        pk.x = pack_bf2(acc[i][0], acc[i][1]);
        pk.y = pack_bf2(acc[i][2], acc[i][3]);
        pk.z = pack_bf2(acc[i][4], acc[i][5]);
        pk.w = pack_bf2(acc[i][6], acc[i][7]);
        h4[(size_t)row * 16 + cx] = pk;

        float vs = 0.f, vd = 0.f;
#pragma unroll
        for (int c = 0; c < 8; ++c) {
            vs = fmaf(acc[i][c], as8[c], vs);
            vd = fmaf(acc[i][c], ad8[c], vd);
        }
        // reduce across the 4 cx values of this head (lanes cx^1, cx^2)
        vs += __shfl_xor(vs, 1); vd += __shfl_xor(vd, 1);
        vs += __shfl_xor(vs, 2); vd += __shfl_xor(vd, 2);
        if ((cx & 3) == 0) {
            a_src[row * 4 + head] = vs;
            a_dst[row * 4 + head] = vd;
        }
    }
}

// ---------------------------------------------------------------------------
// K2: bucket histogram, LDS-privatized. 512 blocks x 3125 edges.
// ---------------------------------------------------------------------------
#define BH_EPB 3125
__global__ __launch_bounds__(256) void bucket_hist_kernel(
    const int* __restrict__ dst, int* __restrict__ bcnt)
{
    __shared__ int cnt[NB_BUCKET];
    const int tid = threadIdx.x;
    for (int i = tid; i < NB_BUCKET; i += 256) cnt[i] = 0;
    __syncthreads();
    const int e0 = blockIdx.x * BH_EPB;
    for (int i = tid; i < BH_EPB; i += 256)
        atomicAdd(&cnt[dst[e0 + i] >> 7], 1);
    __syncthreads();
    for (int i = tid; i < NB_BUCKET; i += 256)
        if (cnt[i]) atomicAdd(&bcnt[i], cnt[i]);
}

// ---------------------------------------------------------------------------
// K3: scan 782 bucket counts. One block, 1024 threads.
// ---------------------------------------------------------------------------
__global__ __launch_bounds__(1024) void bucket_scan_kernel(
    const int* __restrict__ bcnt, int* __restrict__ boff, int* __restrict__ bcur)
{
    const int tid  = threadIdx.x;
    const int lane = tid & 63;
    const int wv   = tid >> 6;
    const int v    = (tid < NB_BUCKET) ? bcnt[tid] : 0;

    int sv = v;
#pragma unroll
    for (int off = 1; off < 64; off <<= 1) {
        int u = __shfl_up(sv, off);
        if (lane >= off) sv += u;
    }
    __shared__ int wsum[16];
    if (lane == 63) wsum[wv] = sv;
    __syncthreads();
    if (tid == 0) {
        int run = 0;
#pragma unroll
        for (int k = 0; k < 16; ++k) { int t = wsum[k]; wsum[k] = run; run += t; }
    }
    __syncthreads();
    if (tid < NB_BUCKET) {
        const int excl = wsum[wv] + sv - v;
        boff[tid] = excl;
        bcur[tid] = excl;
    }
    if (tid == 0) boff[NB_BUCKET] = N_EDGES;
}

// ---------------------------------------------------------------------------
// K4: bucketed scatter with per-block chunk claiming. 512 blocks x 3125 edges.
// ---------------------------------------------------------------------------
#define S1_EPB 3125
__global__ __launch_bounds__(256) void scat1_kernel(
    const int* __restrict__ src, const int* __restrict__ dst,
    int* __restrict__ bcur, unsigned int* __restrict__ tmp)
{
    __shared__ int cnt[NB_BUCKET];
    const int tid = threadIdx.x;
    for (int i = tid; i < NB_BUCKET; i += 256) cnt[i] = 0;
    __syncthreads();
    const int e0 = blockIdx.x * S1_EPB;
    for (int i = tid; i < S1_EPB; i += 256)
        atomicAdd(&cnt[dst[e0 + i] >> 7], 1);
    __syncthreads();
    for (int b = tid; b < NB_BUCKET; b += 256) {
        const int c = cnt[b];
        cnt[b] = c ? atomicAdd(&bcur[b], c) : 0;
    }
    __syncthreads();
    for (int i = tid; i < S1_EPB; i += 256) {
        const int d = dst[e0 + i];
        const int s = src[e0 + i];
        const int p = atomicAdd(&cnt[d >> 7], 1);
        tmp[p] = ((unsigned int)s << 7) | (unsigned int)(d & 127);
    }
}

// ---------------------------------------------------------------------------
// K5: per-bucket finalize -> offs + csr (unchanged)
// ---------------------------------------------------------------------------
__global__ __launch_bounds__(256) void phaseB_kernel(
    const unsigned int* __restrict__ tmp, const int* __restrict__ boff,
    int* __restrict__ offs, int* __restrict__ csr)
{
    __shared__ unsigned int st[ST_CAP];
    __shared__ int hist[128];
    __shared__ int cur[128];
    __shared__ int wtot[4];

    const int b    = blockIdx.x;
    const int tid  = threadIdx.x;
    const int lane = tid & 63;
    const int wv   = tid >> 6;
    const int base = boff[b];
    const int cnt  = boff[b + 1] - base;

    if (tid < 128) hist[tid] = 0;
    __syncthreads();

    for (int i = tid; i < cnt; i += 256) {
        const unsigned int v = tmp[base + i];
        if (i < ST_CAP) st[i] = v;
        atomicAdd(&hist[v & 127], 1);
    }
    __syncthreads();

    const int hv = (tid < 128) ? hist[tid] : 0;
    int sv = hv;
#pragma unroll
    for (int off = 1; off < 64; off <<= 1) {
        int u = __shfl_up(sv, off);
        if (lane >= off) sv += u;
    }
    if (lane == 63) wtot[wv] = sv;
    __syncthreads();
    const int wpre = (wv > 0 ? wtot[0] : 0) + (wv > 1 ? wtot[1] : 0);
    if (tid < 128) {
        const int excl = wpre + sv - hv;
        cur[tid] = excl;
        const int node = (b << 7) + tid;
        if (node < N_NODES) offs[node] = base + excl;
    }
    if (b == 0 && tid == 0) offs[N_NODES] = N_EDGES;
    __syncthreads();

    for (int i = tid; i < cnt; i += 256) {
        const unsigned int v = (i < ST_CAP) ? st[i] : tmp[base + i];
        const int p = atomicAdd(&cur[v & 127], 1);
        csr[base + p] = (int)(v >> 7);
    }
}

// ---------------------------------------------------------------------------
// K6: fused softmax + aggregate + ELU. One wave per node; quarter-wave/edge.
// lane = q*16 + l16 : quarter q handles edges j+q; lane covers ch l16*8..+7.
// ---------------------------------------------------------------------------
__global__ __launch_bounds__(256) void gat_agg_kernel(
    const int* __restrict__ csr_src, const int* __restrict__ offs,
    const uint4* __restrict__ h4,
    const float* __restrict__ a_src, const float* __restrict__ a_dst,
    const float* __restrict__ bias, float* __restrict__ out)
{
    __shared__ float2 st[4][4][68];   // [wave][head][edge] — conflict-free
    __shared__ int s_nch[4];

    const int wv   = threadIdx.x >> 6;
    const int lane = threadIdx.x & 63;
    const int node = blockIdx.x * 4 + wv;
    const int q    = lane >> 4;
    const int l16  = lane & 15;
    const int hq   = l16 >> 2;          // head of this lane's channels

    const int start = offs[node];
    const int deg   = offs[node + 1] - start;
    const float4 ad4 = ((const float4*)a_dst)[node];

    if (lane == 0) s_nch[wv] = (deg + 63) >> 6;
    __syncthreads();
    const int cmax = max(max(s_nch[0], s_nch[1]), max(s_nch[2], s_nch[3]));

    float acc[8];
#pragma unroll
    for (int c = 0; c < 8; ++c) acc[c] = 0.f;
    float den = 0.f;

    for (int ch = 0; ch < cmax; ++ch) {
        const int base = ch << 6;
        const int rem  = deg - base;     // may be <= 0 for this wave

        float sf = 0.f, e0 = 0.f, e1 = 0.f, e2 = 0.f, e3 = 0.f;
        if (lane < rem) {
            const int s = csr_src[start + base + lane];
            sf = __int_as_float(s);
            const float4 as4 = ((const float4*)a_src)[s];
            e0 = __expf(leaky(as4.x + ad4.x));
            e1 = __expf(leaky(as4.y + ad4.y));
            e2 = __expf(leaky(as4.z + ad4.z));
            e3 = __expf(leaky(as4.w + ad4.w));
        }
        st[wv][0][lane] = make_float2(sf, e0);
        st[wv][1][lane] = make_float2(sf, e1);
        st[wv][2][lane] = make_float2(sf, e2);
        st[wv][3][lane] = make_float2(sf, e3);
        __syncthreads();

        const int cnt4 = rem > 0 ? ((rem > 64 ? 64 : (rem + 3) & ~3)) : 0;
        const float2* sp = &st[wv][hq][q];
        for (int j = 0; j < cnt4; j += 4) {
            const float2 se = sp[j];                       // {srcbits, ex}
            const unsigned int soff =
                (__float_as_uint(se.x) << 4) + (unsigned int)l16;
            const uint4 hv = h4[soff];
            const float ex = se.y;
            acc[0] = fmaf(bf_lo(hv.x), ex, acc[0]);
            acc[1] = fmaf(bf_hi(hv.x), ex, acc[1]);
            acc[2] = fmaf(bf_lo(hv.y), ex, acc[2]);
            acc[3] = fmaf(bf_hi(hv.y), ex, acc[3]);
            acc[4] = fmaf(bf_lo(hv.z), ex, acc[4]);
            acc[5] = fmaf(bf_hi(hv.z), ex, acc[5]);
            acc[6] = fmaf(bf_lo(hv.w), ex, acc[6]);
            acc[7] = fmaf(bf_hi(hv.w), ex, acc[7]);
            den += ex;
        }
        __syncthreads();
    }

    // reduce partials across the 4 quarters (lanes l16, l16+16, +32, +48)
#pragma unroll
    for (int c = 0; c < 8; ++c) {
        acc[c] += __shfl_xor(acc[c], 16);
        acc[c] += __shfl_xor(acc[c], 32);
    }
    den += __shfl_xor(den, 16);
    den += __shfl_xor(den, 32);

    if (q == 0) {
        const float inv = 1.0f / (den + 1e-16f);
        const float4 b0 = ((const float4*)bias)[l16 * 2];
        const float4 b1 = ((const float4*)bias)[l16 * 2 + 1];
        float o[8];
        o[0] = acc[0] * inv + b0.x; o[1] = acc[1] * inv + b0.y;
        o[2] = acc[2] * inv + b0.z; o[3] = acc[3] * inv + b0.w;
        o[4] = acc[4] * inv + b1.x; o[5] = acc[5] * inv + b1.y;
        o[6] = acc[6] * inv + b1.z; o[7] = acc[7] * inv + b1.w;
#pragma unroll
        for (int c = 0; c < 8; ++c)
            o[c] = o[c] > 0.f ? o[c] : expm1f(o[c]);
        float4* op = (float4*)&out[(size_t)node * 128 + l16 * 8];
        op[0] = make_float4(o[0], o[1], o[2], o[3]);
        op[1] = make_float4(o[4], o[5], o[6], o[7]);
    }
}

// ---------------------------------------------------------------------------
extern "C" void kernel_launch(void* const* d_in, const int* in_sizes, int n_in,
                              void* d_out, int out_size, void* d_ws, size_t ws_size,
                              hipStream_t stream)
{
    const float* x       = (const float*)d_in[0];
    const int*   ei      = (const int*)  d_in[1];
    const float* W       = (const float*)d_in[2];
    const float* att_src = (const float*)d_in[3];
    const float* att_dst = (const float*)d_in[4];
    const float* bias    = (const float*)d_in[5];
    float*       out     = (float*)d_out;

    char* ws = (char*)d_ws;
    uint4* h4    = (uint4*)(ws + OFF_H);
    float* a_src = (float*)(ws + OFF_ASRC);
    float* a_dst = (float*)(ws + OFF_ADST);
    int*   offs  = (int*)  (ws + OFF_OFFS);
    int*   bcnt  = (int*)  (ws + OFF_BCNT);
    int*   boff  = (int*)  (ws + OFF_BOFF);
    int*   bcur  = (int*)  (ws + OFF_BCUR);
    unsigned int* tmp = (unsigned int*)(ws + OFF_TMP);
    int*   csr   = (int*)  (ws + OFF_CSR);

    const int* srcp = ei;
    const int* dstp = ei + N_EDGES;

    hipMemsetAsync(bcnt, 0, NB_BUCKET * sizeof(int), stream);

    gemm_att_kernel<<<(N_NODES + BR2 - 1) / BR2, 256, 0, stream>>>(
        x, W, att_src, att_dst, h4, a_src, a_dst);

    bucket_hist_kernel<<<N_EDGES / BH_EPB, 256, 0, stream>>>(dstp, bcnt);
    bucket_scan_kernel<<<1, 1024, 0, stream>>>(bcnt, boff, bcur);
    scat1_kernel<<<N_EDGES / S1_EPB, 256, 0, stream>>>(srcp, dstp, bcur, tmp);
    phaseB_kernel<<<NB_BUCKET, 256, 0, stream>>>(tmp, boff, offs, csr);

    gat_agg_kernel<<<N_NODES / 4, 256, 0, stream>>>(
        csr, offs, h4, a_src, a_dst, bias, out);
}

// Round 5
// 298.361 us; speedup vs baseline: 1.0060x; 1.0060x over previous
//
#include <hip/hip_runtime.h>
#include <hip/hip_bf16.h>
#include <math.h>

#define N_NODES 100000
#define N_EDGES 1600000
#define NEG_SLOPE 0.2f

// bucket = dst >> 7 : 128 nodes per bucket
#define NB_BUCKET 782
#define ST_CAP 2560

// ---- workspace layout (bytes) ----
#define OFF_H     0              // N*128 bf16 = 25,600,000
#define OFF_ASRC  25600000       // N*4 f32
#define OFF_ADST  27200000       // N*4 f32
#define OFF_OFFS  28800000       // (N+1) int (pad)
#define OFF_BCNT  29200128       // 782 int (pad 4096)
#define OFF_BOFF  29204224       // 783 int (pad 4096)
#define OFF_BCUR  29208320       // 782 int (pad 4096)
#define OFF_WHI   29212416       // W hi fragments: 4*8*64*16 B = 32768
#define OFF_WLO   29245184       // W lo fragments: 32768
#define OFF_TMP   29277952       // E uint
#define OFF_CSR   35677952       // E int
// total ≈ 42.1 MB

typedef short short8 __attribute__((ext_vector_type(8)));
typedef float floatx4 __attribute__((ext_vector_type(4)));

__device__ __forceinline__ float leaky(float x) {
    return fmaxf(x, NEG_SLOPE * x);
}
__device__ __forceinline__ float bf_lo(unsigned int u) {
    return __uint_as_float(u << 16);
}
__device__ __forceinline__ float bf_hi(unsigned int u) {
    return __uint_as_float(u & 0xffff0000u);
}
// split a pair of fp32 into packed bf16 hi (truncated) and bf16 lo (residual)
__device__ __forceinline__ void split_pack(float a0, float a1,
                                           unsigned int& hi, unsigned int& lo) {
    const unsigned int u0 = __float_as_uint(a0);
    const unsigned int u1 = __float_as_uint(a1);
    hi = (u0 >> 16) | (u1 & 0xffff0000u);
    const float l0 = a0 - __uint_as_float(u0 & 0xffff0000u);
    const float l1 = a1 - __uint_as_float(u1 & 0xffff0000u);
    lo = (__float_as_uint(l0) >> 16) | (__float_as_uint(l1) & 0xffff0000u);
}

// ---------------------------------------------------------------------------
// K0: lay W out in MFMA B-fragment order, split into bf16 hi/lo.
// frag element for lane: B[k = kt*32 + quad*8 + j][n = nt*16 + (lane&15)]
// stored as uint4 at whi[(kt*8 + nt)*64 + lane]. 8 blocks x 256 = 2048 thr.
// ---------------------------------------------------------------------------
__global__ __launch_bounds__(256) void wfrag_kernel(
    const float* __restrict__ W, uint4* __restrict__ whi, uint4* __restrict__ wlo)
{
    const int t    = blockIdx.x * 256 + threadIdx.x;   // 0..2047
    const int lane = t & 63;
    const int nt   = (t >> 6) & 7;
    const int kt   = t >> 9;                           // 0..3
    const int c    = lane & 15;
    const int quad = lane >> 4;
    const int n    = nt * 16 + c;
    const int k0   = kt * 32 + quad * 8;

    unsigned int hu[4], lu[4];
#pragma unroll
    for (int j = 0; j < 4; ++j) {
        const float a0 = W[(size_t)(k0 + 2 * j) * 128 + n];
        const float a1 = W[(size_t)(k0 + 2 * j + 1) * 128 + n];
        split_pack(a0, a1, hu[j], lu[j]);
    }
    whi[(kt * 8 + nt) * 64 + lane] = make_uint4(hu[0], hu[1], hu[2], hu[3]);
    wlo[(kt * 8 + nt) * 64 + lane] = make_uint4(lu[0], lu[1], lu[2], lu[3]);
}

// ---------------------------------------------------------------------------
// K1: h = x @ W via bf16x3 MFMA (fp32-grade). 512 thr = 8 waves.
// wave (rw, cw): rows blockIdx*256 + rw*64 .. +63, cols cw*64 .. +63.
// A frags straight from global x (32 B/lane contiguous), B frags from wfrag.
// Fused epilogue: bf16 h store + a_src/a_dst via intra-quad shuffle reduce.
// C/D layout (m89): col = lane&15, row = quad*4 + reg.
// ---------------------------------------------------------------------------
__global__ __launch_bounds__(512, 1) void gemm_mfma_kernel(
    const float* __restrict__ x, const uint4* __restrict__ whi,
    const uint4* __restrict__ wlo, const float* __restrict__ att_src,
    const float* __restrict__ att_dst, unsigned short* __restrict__ h_bf,
    float* __restrict__ a_src, float* __restrict__ a_dst)
{
    const int wave = threadIdx.x >> 6;
    const int lane = threadIdx.x & 63;
    const int rw   = wave >> 1;
    const int cw   = wave & 1;
    const int row0 = blockIdx.x * 256 + rw * 64;
    const int c    = lane & 15;
    const int quad = lane >> 4;

    floatx4 acc[4][4];
#pragma unroll
    for (int i = 0; i < 4; ++i)
#pragma unroll
        for (int j = 0; j < 4; ++j) acc[i][j] = (floatx4){0.f, 0.f, 0.f, 0.f};

    for (int kt = 0; kt < 4; ++kt) {
        short8 ahi[4], alo[4];
#pragma unroll
        for (int rt = 0; rt < 4; ++rt) {
            int r = row0 + rt * 16 + c;
            if (r >= N_NODES) r = N_NODES - 1;
            const float4* xp = (const float4*)&x[(size_t)r * 128 + kt * 32 + quad * 8];
            const float4 v0 = xp[0];
            const float4 v1 = xp[1];
            const float xv[8] = {v0.x, v0.y, v0.z, v0.w, v1.x, v1.y, v1.z, v1.w};
            union { short8 v; unsigned int u[4]; } H, L;
#pragma unroll
            for (int j = 0; j < 4; ++j)
                split_pack(xv[2 * j], xv[2 * j + 1], H.u[j], L.u[j]);
            ahi[rt] = H.v;
            alo[rt] = L.v;
        }
#pragma unroll
        for (int nt = 0; nt < 4; ++nt) {
            const int nti = cw * 4 + nt;
            union { uint4 q; short8 v; } BH, BL;
            BH.q = whi[(kt * 8 + nti) * 64 + lane];
            BL.q = wlo[(kt * 8 + nti) * 64 + lane];
#pragma unroll
            for (int rt = 0; rt < 4; ++rt) {
                acc[rt][nt] = __builtin_amdgcn_mfma_f32_16x16x32_bf16(
                    ahi[rt], BH.v, acc[rt][nt], 0, 0, 0);
                acc[rt][nt] = __builtin_amdgcn_mfma_f32_16x16x32_bf16(
                    alo[rt], BH.v, acc[rt][nt], 0, 0, 0);
                acc[rt][nt] = __builtin_amdgcn_mfma_f32_16x16x32_bf16(
                    ahi[rt], BL.v, acc[rt][nt], 0, 0, 0);
            }
        }
    }

    // ---- epilogue ----
    const int cb = cw * 64;
    float asv[4], adv[4];
#pragma unroll
    for (int nt = 0; nt < 4; ++nt) {
        asv[nt] = att_src[cb + nt * 16 + c];
        adv[nt] = att_dst[cb + nt * 16 + c];
    }

#pragma unroll
    for (int rt = 0; rt < 4; ++rt) {
        const int rbase = row0 + rt * 16 + quad * 4;
        // h store (bf16 scalar; 4 rows x 32 B contiguous per inst)
#pragma unroll
        for (int reg = 0; reg < 4; ++reg) {
            const int row = rbase + reg;
            if (row < N_NODES) {
#pragma unroll
                for (int nt = 0; nt < 4; ++nt)
                    h_bf[(size_t)row * 128 + cb + nt * 16 + c] =
                        __bfloat16_as_ushort(__float2bfloat16(acc[rt][nt][reg]));
            }
        }
        // attention partials: head = 2*cw + hl over col-tile pair {2hl, 2hl+1}
#pragma unroll
        for (int hl = 0; hl < 2; ++hl) {
#pragma unroll
            for (int reg = 0; reg < 4; ++reg) {
                float ps = acc[rt][2 * hl][reg] * asv[2 * hl]
                         + acc[rt][2 * hl + 1][reg] * asv[2 * hl + 1];
                float pd = acc[rt][2 * hl][reg] * adv[2 * hl]
                         + acc[rt][2 * hl + 1][reg] * adv[2 * hl + 1];
#pragma unroll
                for (int off = 1; off < 16; off <<= 1) {
                    ps += __shfl_xor(ps, off);
                    pd += __shfl_xor(pd, off);
                }
                const int row = rbase + reg;
                if (c == 0 && row < N_NODES) {
                    a_src[row * 4 + 2 * cw + hl] = ps;
                    a_dst[row * 4 + 2 * cw + hl] = pd;
                }
            }
        }
    }
}

// ---------------------------------------------------------------------------
// K2: bucket histogram, LDS-privatized. 512 blocks x 3125 edges.
// ---------------------------------------------------------------------------
#define BH_EPB 3125
__global__ __launch_bounds__(256) void bucket_hist_kernel(
    const int* __restrict__ dst, int* __restrict__ bcnt)
{
    __shared__ int cnt[NB_BUCKET];
    const int tid = threadIdx.x;
    for (int i = tid; i < NB_BUCKET; i += 256) cnt[i] = 0;
    __syncthreads();
    const int e0 = blockIdx.x * BH_EPB;
    for (int i = tid; i < BH_EPB; i += 256)
        atomicAdd(&cnt[dst[e0 + i] >> 7], 1);
    __syncthreads();
    for (int i = tid; i < NB_BUCKET; i += 256)
        if (cnt[i]) atomicAdd(&bcnt[i], cnt[i]);
}

// ---------------------------------------------------------------------------
// K3: scan 782 bucket counts. One block, 1024 threads.
// ---------------------------------------------------------------------------
__global__ __launch_bounds__(1024) void bucket_scan_kernel(
    const int* __restrict__ bcnt, int* __restrict__ boff, int* __restrict__ bcur)
{
    const int tid  = threadIdx.x;
    const int lane = tid & 63;
    const int wv   = tid >> 6;
    const int v    = (tid < NB_BUCKET) ? bcnt[tid] : 0;

    int sv = v;
#pragma unroll
    for (int off = 1; off < 64; off <<= 1) {
        int u = __shfl_up(sv, off);
        if (lane >= off) sv += u;
    }
    __shared__ int wsum[16];
    if (lane == 63) wsum[wv] = sv;
    __syncthreads();
    if (tid == 0) {
        int run = 0;
#pragma unroll
        for (int k = 0; k < 16; ++k) { int t = wsum[k]; wsum[k] = run; run += t; }
    }
    __syncthreads();
    if (tid < NB_BUCKET) {
        const int excl = wsum[wv] + sv - v;
        boff[tid] = excl;
        bcur[tid] = excl;
    }
    if (tid == 0) boff[NB_BUCKET] = N_EDGES;
}

// ---------------------------------------------------------------------------
// K4: bucketed scatter with per-block chunk claiming. 512 blocks x 3125 edges.
// ---------------------------------------------------------------------------
#define S1_EPB 3125
__global__ __launch_bounds__(256) void scat1_kernel(
    const int* __restrict__ src, const int* __restrict__ dst,
    int* __restrict__ bcur, unsigned int* __restrict__ tmp)
{
    __shared__ int cnt[NB_BUCKET];
    const int tid = threadIdx.x;
    for (int i = tid; i < NB_BUCKET; i += 256) cnt[i] = 0;
    __syncthreads();
    const int e0 = blockIdx.x * S1_EPB;
    for (int i = tid; i < S1_EPB; i += 256)
        atomicAdd(&cnt[dst[e0 + i] >> 7], 1);
    __syncthreads();
    for (int b = tid; b < NB_BUCKET; b += 256) {
        const int c = cnt[b];
        cnt[b] = c ? atomicAdd(&bcur[b], c) : 0;
    }
    __syncthreads();
    for (int i = tid; i < S1_EPB; i += 256) {
        const int d = dst[e0 + i];
        const int s = src[e0 + i];
        const int p = atomicAdd(&cnt[d >> 7], 1);
        tmp[p] = ((unsigned int)s << 7) | (unsigned int)(d & 127);
    }
}

// ---------------------------------------------------------------------------
// K5: per-bucket finalize -> offs + csr
// ---------------------------------------------------------------------------
__global__ __launch_bounds__(256) void phaseB_kernel(
    const unsigned int* __restrict__ tmp, const int* __restrict__ boff,
    int* __restrict__ offs, int* __restrict__ csr)
{
    __shared__ unsigned int st[ST_CAP];
    __shared__ int hist[128];
    __shared__ int cur[128];
    __shared__ int wtot[4];

    const int b    = blockIdx.x;
    const int tid  = threadIdx.x;
    const int lane = tid & 63;
    const int wv   = tid >> 6;
    const int base = boff[b];
    const int cnt  = boff[b + 1] - base;

    if (tid < 128) hist[tid] = 0;
    __syncthreads();

    for (int i = tid; i < cnt; i += 256) {
        const unsigned int v = tmp[base + i];
        if (i < ST_CAP) st[i] = v;
        atomicAdd(&hist[v & 127], 1);
    }
    __syncthreads();

    const int hv = (tid < 128) ? hist[tid] : 0;
    int sv = hv;
#pragma unroll
    for (int off = 1; off < 64; off <<= 1) {
        int u = __shfl_up(sv, off);
        if (lane >= off) sv += u;
    }
    if (lane == 63) wtot[wv] = sv;
    __syncthreads();
    const int wpre = (wv > 0 ? wtot[0] : 0) + (wv > 1 ? wtot[1] : 0);
    if (tid < 128) {
        const int excl = wpre + sv - hv;
        cur[tid] = excl;
        const int node = (b << 7) + tid;
        if (node < N_NODES) offs[node] = base + excl;
    }
    if (b == 0 && tid == 0) offs[N_NODES] = N_EDGES;
    __syncthreads();

    for (int i = tid; i < cnt; i += 256) {
        const unsigned int v = (i < ST_CAP) ? st[i] : tmp[base + i];
        const int p = atomicAdd(&cur[v & 127], 1);
        csr[base + p] = (int)(v >> 7);
    }
}

// ---------------------------------------------------------------------------
// K6: fused softmax + aggregate + ELU. One wave per node; quarter-wave/edge.
// ---------------------------------------------------------------------------
__global__ __launch_bounds__(256) void gat_agg_kernel(
    const int* __restrict__ csr_src, const int* __restrict__ offs,
    const uint4* __restrict__ h4,
    const float* __restrict__ a_src, const float* __restrict__ a_dst,
    const float* __restrict__ bias, float* __restrict__ out)
{
    __shared__ float2 st[4][4][68];   // [wave][head][edge] — conflict-free
    __shared__ int s_nch[4];

    const int wv   = threadIdx.x >> 6;
    const int lane = threadIdx.x & 63;
    const int node = blockIdx.x * 4 + wv;
    const int q    = lane >> 4;
    const int l16  = lane & 15;
    const int hq   = l16 >> 2;

    const int start = offs[node];
    const int deg   = offs[node + 1] - start;
    const float4 ad4 = ((const float4*)a_dst)[node];

    if (lane == 0) s_nch[wv] = (deg + 63) >> 6;
    __syncthreads();
    const int cmax = max(max(s_nch[0], s_nch[1]), max(s_nch[2], s_nch[3]));

    float acc[8];
#pragma unroll
    for (int c = 0; c < 8; ++c) acc[c] = 0.f;
    float den = 0.f;

    for (int ch = 0; ch < cmax; ++ch) {
        const int base = ch << 6;
        const int rem  = deg - base;

        float sf = 0.f, e0 = 0.f, e1 = 0.f, e2 = 0.f, e3 = 0.f;
        if (lane < rem) {
            const int s = csr_src[start + base + lane];
            sf = __int_as_float(s);
            const float4 as4 = ((const float4*)a_src)[s];
            e0 = __expf(leaky(as4.x + ad4.x));
            e1 = __expf(leaky(as4.y + ad4.y));
            e2 = __expf(leaky(as4.z + ad4.z));
            e3 = __expf(leaky(as4.w + ad4.w));
        }
        st[wv][0][lane] = make_float2(sf, e0);
        st[wv][1][lane] = make_float2(sf, e1);
        st[wv][2][lane] = make_float2(sf, e2);
        st[wv][3][lane] = make_float2(sf, e3);
        __syncthreads();

        const int cnt4 = rem > 0 ? ((rem > 64 ? 64 : (rem + 3) & ~3)) : 0;
        const float2* sp = &st[wv][hq][q];
        for (int j = 0; j < cnt4; j += 4) {
            const float2 se = sp[j];
            const unsigned int soff =
                (__float_as_uint(se.x) << 4) + (unsigned int)l16;
            const uint4 hv = h4[soff];
            const float ex = se.y;
            acc[0] = fmaf(bf_lo(hv.x), ex, acc[0]);
            acc[1] = fmaf(bf_hi(hv.x), ex, acc[1]);
            acc[2] = fmaf(bf_lo(hv.y), ex, acc[2]);
            acc[3] = fmaf(bf_hi(hv.y), ex, acc[3]);
            acc[4] = fmaf(bf_lo(hv.z), ex, acc[4]);
            acc[5] = fmaf(bf_hi(hv.z), ex, acc[5]);
            acc[6] = fmaf(bf_lo(hv.w), ex, acc[6]);
            acc[7] = fmaf(bf_hi(hv.w), ex, acc[7]);
            den += ex;
        }
        __syncthreads();
    }

#pragma unroll
    for (int c = 0; c < 8; ++c) {
        acc[c] += __shfl_xor(acc[c], 16);
        acc[c] += __shfl_xor(acc[c], 32);
    }
    den += __shfl_xor(den, 16);
    den += __shfl_xor(den, 32);

    if (q == 0) {
        const float inv = 1.0f / (den + 1e-16f);
        const float4 b0 = ((const float4*)bias)[l16 * 2];
        const float4 b1 = ((const float4*)bias)[l16 * 2 + 1];
        float o[8];
        o[0] = acc[0] * inv + b0.x; o[1] = acc[1] * inv + b0.y;
        o[2] = acc[2] * inv + b0.z; o[3] = acc[3] * inv + b0.w;
        o[4] = acc[4] * inv + b1.x; o[5] = acc[5] * inv + b1.y;
        o[6] = acc[6] * inv + b1.z; o[7] = acc[7] * inv + b1.w;
#pragma unroll
        for (int c = 0; c < 8; ++c)
            o[c] = o[c] > 0.f ? o[c] : expm1f(o[c]);
        float4* op = (float4*)&out[(size_t)node * 128 + l16 * 8];
        op[0] = make_float4(o[0], o[1], o[2], o[3]);
        op[1] = make_float4(o[4], o[5], o[6], o[7]);
    }
}

// ---------------------------------------------------------------------------
extern "C" void kernel_launch(void* const* d_in, const int* in_sizes, int n_in,
                              void* d_out, int out_size, void* d_ws, size_t ws_size,
                              hipStream_t stream)
{
    const float* x       = (const float*)d_in[0];
    const int*   ei      = (const int*)  d_in[1];
    const float* W       = (const float*)d_in[2];
    const float* att_src = (const float*)d_in[3];
    const float* att_dst = (const float*)d_in[4];
    const float* bias    = (const float*)d_in[5];
    float*       out     = (float*)d_out;

    char* ws = (char*)d_ws;
    unsigned short* h_bf = (unsigned short*)(ws + OFF_H);
    uint4* h4    = (uint4*)(ws + OFF_H);
    float* a_src = (float*)(ws + OFF_ASRC);
    float* a_dst = (float*)(ws + OFF_ADST);
    int*   offs  = (int*)  (ws + OFF_OFFS);
    int*   bcnt  = (int*)  (ws + OFF_BCNT);
    int*   boff  = (int*)  (ws + OFF_BOFF);
    int*   bcur  = (int*)  (ws + OFF_BCUR);
    uint4* whi   = (uint4*)(ws + OFF_WHI);
    uint4* wlo   = (uint4*)(ws + OFF_WLO);
    unsigned int* tmp = (unsigned int*)(ws + OFF_TMP);
    int*   csr   = (int*)  (ws + OFF_CSR);

    const int* srcp = ei;
    const int* dstp = ei + N_EDGES;

    hipMemsetAsync(bcnt, 0, NB_BUCKET * sizeof(int), stream);

    wfrag_kernel<<<8, 256, 0, stream>>>(W, whi, wlo);
    gemm_mfma_kernel<<<(N_NODES + 255) / 256, 512, 0, stream>>>(
        x, whi, wlo, att_src, att_dst, h_bf, a_src, a_dst);

    bucket_hist_kernel<<<N_EDGES / BH_EPB, 256, 0, stream>>>(dstp, bcnt);
    bucket_scan_kernel<<<1, 1024, 0, stream>>>(bcnt, boff, bcur);
    scat1_kernel<<<N_EDGES / S1_EPB, 256, 0, stream>>>(srcp, dstp, bcur, tmp);
    phaseB_kernel<<<NB_BUCKET, 256, 0, stream>>>(tmp, boff, offs, csr);

    gat_agg_kernel<<<N_NODES / 4, 256, 0, stream>>>(
        csr, offs, h4, a_src, a_dst, bias, out);
}